// Round 10
// baseline (155.725 us; speedup 1.0000x reference)
//
#include <hip/hip_runtime.h>

#define Bb 64
#define Nn 8192
#define Ff 32
#define Gg 32
#define G3 (Gg*Gg*Gg)          // 32768
#define NATOM (Bb*Nn)          // 524288
#define NBINS (Bb*G3)          // 2^21

// ---------------- ws layout ----------------
// [0,1024)        centers (fallback only)
// [1024, +8MB)    meta[NBINS] u32: (end_local<<16)|cnt   (end,cnt <= 8192)
// [+2MB)          atomIdx[NATOM] u32 (global atom id, bin-sorted)
// [+64MB)         gSorted[NATOM*Ff] f32 (per-atom W*f+b, bin-sorted order)
static const size_t WS_CENTERS = 0;
static const size_t WS_META    = 1024;
static const size_t WS_AIDX    = WS_META + (size_t)NBINS * 4;
static const size_t WS_GS      = WS_AIDX + (size_t)NATOM * 4;
static const size_t WS_NEED    = WS_GS + (size_t)NATOM * Ff * 4;

// One block per batch (1024 threads, 8 atoms/thread): fp64 centroid ->
// two-pass LDS histogram -> in-LDS scan -> meta + LDS-atomic placement.
__global__ void __launch_bounds__(1024) fused_sort_kernel(const float* __restrict__ coords,
                                                          unsigned* __restrict__ meta,
                                                          unsigned* __restrict__ atomIdx) {
    __shared__ unsigned long long lds8[8192];      // 64 KB, 8B-aligned
    unsigned* hist = (unsigned*)lds8;              // [16384] bins per pass
    double*   dred = (double*)lds8;                // [1024*3] centroid reduction

    const int b = blockIdx.x;
    const int t = threadIdx.x;
    const int wave = t >> 6, lane = t & 63;

    float ax[8], ay[8], az[8];
    const float* cb = coords + (size_t)b * Nn * 3;
    #pragma unroll
    for (int i = 0; i < 8; ++i) {
        const int n = t + 1024 * i;
        ax[i] = cb[n * 3 + 0]; ay[i] = cb[n * 3 + 1]; az[i] = cb[n * 3 + 2];
    }

    double sx = 0.0, sy = 0.0, sz = 0.0;
    #pragma unroll
    for (int i = 0; i < 8; ++i) { sx += (double)ax[i]; sy += (double)ay[i]; sz += (double)az[i]; }
    dred[t * 3 + 0] = sx; dred[t * 3 + 1] = sy; dred[t * 3 + 2] = sz;
    __syncthreads();
    for (int s = 512; s > 0; s >>= 1) {
        if (t < s) {
            dred[t * 3 + 0] += dred[(t + s) * 3 + 0];
            dred[t * 3 + 1] += dred[(t + s) * 3 + 1];
            dred[t * 3 + 2] += dred[(t + s) * 3 + 2];
        }
        __syncthreads();
    }
    const float cx = (float)(dred[0] * (1.0 / Nn));
    const float cy = (float)(dred[1] * (1.0 / Nn));
    const float cz = (float)(dred[2] * (1.0 / Nn));
    __syncthreads();

    unsigned bin[8];
    #pragma unroll
    for (int i = 0; i < 8; ++i) {
        const int ix = min(max((int)((ax[i] - cx) + 16.0f), 0), Gg - 1);
        const int iy = min(max((int)((ay[i] - cy) + 16.0f), 0), Gg - 1);
        const int iz = min(max((int)((az[i] - cz) + 16.0f), 0), Gg - 1);
        bin[i] = ((unsigned)ix << 10) | ((unsigned)iy << 5) | (unsigned)iz;
    }

    unsigned passbase = 0;
    for (int pass = 0; pass < 2; ++pass) {
        const unsigned lo = (unsigned)pass << 14;
        #pragma unroll
        for (int j = 0; j < 16; ++j) hist[t + 1024 * j] = 0u;
        __syncthreads();
        #pragma unroll
        for (int i = 0; i < 8; ++i)
            if ((bin[i] >> 14) == (unsigned)pass) atomicAdd(&hist[bin[i] & 16383u], 1u);
        __syncthreads();

        const int w0 = t * 16;
        unsigned s = 0;
        #pragma unroll
        for (int j = 0; j < 16; ++j) s += hist[w0 + j] & 0xFFFFu;
        unsigned incl = s;
        #pragma unroll
        for (int d = 1; d < 64; d <<= 1) {
            const unsigned u = __shfl_up(incl, d);
            if (lane >= d) incl += u;
        }
        if (lane == 63) hist[wave] = (hist[wave] & 0xFFFFu) | (incl << 16);
        __syncthreads();
        unsigned wbase = 0, tot = 0;
        #pragma unroll
        for (int w = 0; w < 16; ++w) {
            const unsigned wt = hist[w] >> 16;
            if (w < wave) wbase += wt;
            tot += wt;
        }
        unsigned running = passbase + wbase + (incl - s);
        __syncthreads();
        unsigned* mrow = meta + (size_t)b * 32768 + lo;
        #pragma unroll
        for (int j = 0; j < 16; ++j) {
            const unsigned c = hist[w0 + j] & 0xFFFFu;
            hist[w0 + j] = running;
            mrow[w0 + j] = ((running + c) << 16) | c;
            running += c;
        }
        __syncthreads();
        #pragma unroll
        for (int i = 0; i < 8; ++i)
            if ((bin[i] >> 14) == (unsigned)pass) {
                const unsigned pos = atomicAdd(&hist[bin[i] & 16383u], 1u);
                atomIdx[(size_t)b * Nn + pos] = (unsigned)(b * Nn) + (unsigned)(t + 1024 * i);
            }
        __syncthreads();
        passbase = tot;
    }
}

// One thread per sorted slot: gather the atom's features (the only random
// pass, full occupancy, 8 independent float4 loads), apply W*f+b per atom
// (W/bias wave-uniform -> s_load + v_fmac), write g row in SORTED order.
// After this, gather is pure streaming.
__global__ void __launch_bounds__(256) transform_kernel(const unsigned* __restrict__ atomIdx,
                                                        const float* __restrict__ features,
                                                        const float* __restrict__ W,
                                                        const float* __restrict__ bias,
                                                        float* __restrict__ gSorted) {
    const unsigned slot = blockIdx.x * 256 + threadIdx.x;
    const unsigned a = atomIdx[slot];

    float ft[Ff];
    const float4* f4 = reinterpret_cast<const float4*>(features + (size_t)a * Ff);
    #pragma unroll
    for (int q = 0; q < 8; ++q) {
        const float4 v = f4[q];
        ft[4 * q + 0] = v.x; ft[4 * q + 1] = v.y;
        ft[4 * q + 2] = v.z; ft[4 * q + 3] = v.w;
    }

    float4* g4 = reinterpret_cast<float4*>(gSorted + (size_t)slot * Ff);
    #pragma unroll
    for (int f = 0; f < Ff; f += 4) {
        float v0 = bias[f + 0];
        float v1 = bias[f + 1];
        float v2 = bias[f + 2];
        float v3 = bias[f + 3];
        #pragma unroll
        for (int j = 0; j < Ff; ++j) {
            const float x = ft[j];
            v0 += W[(f + 0) * Ff + j] * x;
            v1 += W[(f + 1) * Ff + j] * x;
            v2 += W[(f + 2) * Ff + j] * x;
            v3 += W[(f + 3) * Ff + j] * x;
        }
        g4[f / 4] = make_float4(v0, v1, v2, v3);
    }
}

// One thread per output cell: sum its k CONTIGUOUS g-rows (no indirection,
// addresses independent of load results -> deep pipelining), write coalesced.
__global__ void __launch_bounds__(256) gather_kernel(const unsigned* __restrict__ meta,
                                                     const float* __restrict__ gSorted,
                                                     float* __restrict__ out) {
    const int b = blockIdx.x >> 7;
    const int spatial = ((blockIdx.x & 127) << 8) + threadIdx.x;
    const unsigned m = meta[((size_t)b << 15) + (unsigned)spatial];
    const unsigned k = m & 0xFFFFu;
    float* outb = out + (size_t)b * Ff * G3 + spatial;

    if (!__any((int)k)) {                          // whole wave empty: zero-fill
        #pragma unroll
        for (int f = 0; f < Ff; ++f) outb[(size_t)f * G3] = 0.0f;
        return;
    }

    const unsigned start = ((unsigned)b << 13) + (m >> 16) - k;
    float acc[Ff];
    #pragma unroll
    for (int j = 0; j < Ff; ++j) acc[j] = 0.0f;
    #pragma unroll 2
    for (unsigned i = 0; i < k; ++i) {
        const float4* g4 = reinterpret_cast<const float4*>(gSorted + (size_t)(start + i) * Ff);
        #pragma unroll
        for (int q = 0; q < 8; ++q) {
            const float4 v = g4[q];
            acc[4 * q + 0] += v.x; acc[4 * q + 1] += v.y;
            acc[4 * q + 2] += v.z; acc[4 * q + 3] += v.w;
        }
    }

    #pragma unroll
    for (int f = 0; f < Ff; ++f) outb[(size_t)f * G3] = acc[f];
}

// ---------- fallback (atomic path) if ws is too small ----------
__global__ void __launch_bounds__(256) centers_kernel(const float* __restrict__ coords,
                                                      float* __restrict__ centers) {
    const int b = blockIdx.x;
    const int t = threadIdx.x;
    double sx = 0.0, sy = 0.0, sz = 0.0;
    const float* cb = coords + (size_t)b * Nn * 3;
    for (int n = t; n < Nn; n += 256) {
        sx += (double)cb[n * 3 + 0];
        sy += (double)cb[n * 3 + 1];
        sz += (double)cb[n * 3 + 2];
    }
    __shared__ double red[256][3];
    red[t][0] = sx; red[t][1] = sy; red[t][2] = sz;
    __syncthreads();
    for (int s = 128; s > 0; s >>= 1) {
        if (t < s) {
            red[t][0] += red[t + s][0];
            red[t][1] += red[t + s][1];
            red[t][2] += red[t + s][2];
        }
        __syncthreads();
    }
    if (t < 3) centers[b * 3 + t] = (float)(red[0][t] * (1.0 / Nn));
}

__global__ void __launch_bounds__(256) scatter_kernel(const float* __restrict__ coords,
                                                      const float* __restrict__ features,
                                                      const float* __restrict__ W,
                                                      const float* __restrict__ bias,
                                                      const float* __restrict__ centers,
                                                      float* __restrict__ out) {
    __shared__ float Wl[Ff * Ff];
    __shared__ float bl[Ff];
    for (int i = threadIdx.x; i < Ff * Ff; i += 256) Wl[i] = W[i];
    if (threadIdx.x < Ff) bl[threadIdx.x] = bias[threadIdx.x];
    __syncthreads();
    const int atom = blockIdx.x * 256 + threadIdx.x;
    const int b = atom >> 13;
    const float cx = centers[b * 3 + 0];
    const float cy = centers[b * 3 + 1];
    const float cz = centers[b * 3 + 2];
    const float* cp = coords + (size_t)atom * 3;
    const int ix = min(max((int)((cp[0] - cx) + 16.0f), 0), Gg - 1);
    const int iy = min(max((int)((cp[1] - cy) + 16.0f), 0), Gg - 1);
    const int iz = min(max((int)((cp[2] - cz) + 16.0f), 0), Gg - 1);
    const int spatial = ix * (Gg * Gg) + iy * Gg + iz;
    float* outb = out + (size_t)b * Ff * G3 + spatial;
    float ft[Ff];
    const float4* f4 = reinterpret_cast<const float4*>(features + (size_t)atom * Ff);
    #pragma unroll
    for (int q = 0; q < 8; ++q) {
        const float4 v = f4[q];
        ft[4 * q + 0] = v.x; ft[4 * q + 1] = v.y;
        ft[4 * q + 2] = v.z; ft[4 * q + 3] = v.w;
    }
    #pragma unroll 4
    for (int fo = 0; fo < Ff; ++fo) {
        float a2 = bl[fo];
        #pragma unroll
        for (int j = 0; j < Ff; ++j) a2 += Wl[fo * Ff + j] * ft[j];
        atomicAdd(outb + (size_t)fo * G3, a2);
    }
}

extern "C" void kernel_launch(void* const* d_in, const int* in_sizes, int n_in,
                              void* d_out, int out_size, void* d_ws, size_t ws_size,
                              hipStream_t stream) {
    const float* coords   = (const float*)d_in[0];
    const float* features = (const float*)d_in[1];
    const float* W        = (const float*)d_in[2];
    const float* bias     = (const float*)d_in[3];
    float* out = (float*)d_out;

    char* ws = (char*)d_ws;

    if (ws_size < WS_NEED) {
        float* centers = (float*)(ws + WS_CENTERS);
        hipMemsetAsync(d_out, 0, (size_t)out_size * sizeof(float), stream);
        centers_kernel<<<Bb, 256, 0, stream>>>(coords, centers);
        scatter_kernel<<<(NATOM) / 256, 256, 0, stream>>>(coords, features, W, bias, centers, out);
        return;
    }

    unsigned* meta    = (unsigned*)(ws + WS_META);
    unsigned* atomIdx = (unsigned*)(ws + WS_AIDX);
    float*    gSorted = (float*)(ws + WS_GS);

    fused_sort_kernel<<<Bb, 1024, 0, stream>>>(coords, meta, atomIdx);
    transform_kernel<<<NATOM / 256, 256, 0, stream>>>(atomIdx, features, W, bias, gSorted);
    gather_kernel<<<Bb * (G3 / 256), 256, 0, stream>>>(meta, gSorted, out);
}